// Round 9
// baseline (268.795 us; speedup 1.0000x reference)
//
#include <hip/hip_runtime.h>

#define DIM_C 512
#define HEADS 8
#define HD 64
#define BATCH 2
#define SEQ 4096
#define QSCALE (0.125f * 1.44269504088896f)   // 1/sqrt(64) * log2(e)

typedef __attribute__((ext_vector_type(8))) short short8;
typedef __attribute__((ext_vector_type(4))) float f32x4;

// fp32 -> bf16 round-to-nearest-even
__device__ __forceinline__ ushort f2bf(float f) {
    union { float f; unsigned u; } x; x.f = f;
    unsigned r = x.u + 0x7fffu + ((x.u >> 16) & 1u);
    return (ushort)(r >> 16);
}

// async global->LDS, 16B per lane. LDS dest = wave-uniform base + lane*16.
__device__ __forceinline__ void gl_lds16(const void* g, void* l) {
    __builtin_amdgcn_global_load_lds(
        (const __attribute__((address_space(1))) unsigned int*)g,
        (__attribute__((address_space(3))) unsigned int*)l, 16, 0, 0);
}

__device__ __forceinline__ unsigned cvt_pk_bf16(float lo, float hi) {
    unsigned w;
    asm("v_cvt_pk_bf16_f32 %0, %1, %2" : "=v"(w) : "v"(lo), "v"(hi));
    return w;
}

// ---------------------------------------------------------------------------
// prep kernels (proven)
// ---------------------------------------------------------------------------
__global__ __launch_bounds__(256)
void convert_bf16(const float* __restrict__ in, ushort* __restrict__ out, int n4) {
    int i = blockIdx.x * blockDim.x + threadIdx.x;
    const int stride = gridDim.x * blockDim.x;
    for (; i < n4; i += stride) {
        const float4 v = reinterpret_cast<const float4*>(in)[i];
        ushort4 o;
        o.x = f2bf(v.x); o.y = f2bf(v.y); o.z = f2bf(v.z); o.w = f2bf(v.w);
        reinterpret_cast<ushort4*>(out)[i] = o;
    }
}

__global__ __launch_bounds__(256)
void transpose_w_bf16(const float* __restrict__ in, ushort* __restrict__ out,
                      int R, int C) {
    __shared__ ushort Ls[64 * 68];
    const int tid = threadIdx.x;
    const int c0 = blockIdx.x * 64, r0 = blockIdx.y * 64;
    #pragma unroll
    for (int p = 0; p < 4; ++p) {
        const int idx = tid + p * 256;
        const int r = idx >> 4, c4 = (idx & 15) * 4;
        const float4 v = *reinterpret_cast<const float4*>(
            &in[(size_t)(r0 + r) * C + c0 + c4]);
        ushort4 o; o.x = f2bf(v.x); o.y = f2bf(v.y); o.z = f2bf(v.z); o.w = f2bf(v.w);
        *reinterpret_cast<ushort4*>(&Ls[r * 68 + c4]) = o;
    }
    __syncthreads();
    #pragma unroll
    for (int p = 0; p < 4; ++p) {
        const int idx = tid + p * 256;
        const int c = idx >> 4, r4 = (idx & 15) * 4;
        ushort4 o;
        o.x = Ls[(r4 + 0) * 68 + c]; o.y = Ls[(r4 + 1) * 68 + c];
        o.z = Ls[(r4 + 2) * 68 + c]; o.w = Ls[(r4 + 3) * 68 + c];
        *reinterpret_cast<ushort4*>(&out[(size_t)(c0 + c) * R + r0 + r4]) = o;
    }
}

// V extract+transpose: qkvb [B*N,1536] cols 1024.. -> vt[bh][d=64][n=4096]
__global__ __launch_bounds__(256)
void transpose_v(const ushort* __restrict__ qkvb, ushort* __restrict__ vt) {
    __shared__ ushort Ls[64 * 68];
    const int tid = threadIdx.x;
    const int n0 = blockIdx.x * 64;
    const int bh = blockIdx.y, b = bh >> 3, h = bh & 7;
    #pragma unroll
    for (int p = 0; p < 4; ++p) {
        const int idx = tid + p * 256;
        const int r = idx >> 4, c4 = (idx & 15) * 4;
        const ushort4 v = *reinterpret_cast<const ushort4*>(
            &qkvb[(size_t)(b * SEQ + n0 + r) * 1536 + 1024 + h * 64 + c4]);
        *reinterpret_cast<ushort4*>(&Ls[r * 68 + c4]) = v;
    }
    __syncthreads();
    #pragma unroll
    for (int p = 0; p < 4; ++p) {
        const int idx = tid + p * 256;
        const int d = idx >> 4, n4 = (idx & 15) * 4;
        ushort4 o;
        o.x = Ls[(n4 + 0) * 68 + d]; o.y = Ls[(n4 + 1) * 68 + d];
        o.z = Ls[(n4 + 2) * 68 + d]; o.w = Ls[(n4 + 3) * 68 + d];
        *reinterpret_cast<ushort4*>(&vt[((size_t)bh * 64 + d) * SEQ + n0 + n4]) = o;
    }
}

// ---------------------------------------------------------------------------
// bf16 MFMA GEMM, swapped operands (lane = one C-row, 4 consecutive cols).
// MODE 0: float4 out. MODE 1: ushort4 out, Q cols scaled by QSCALE.
// ---------------------------------------------------------------------------
template<int MODE>
__global__ __launch_bounds__(256)
void gemm_mfma(const ushort* __restrict__ A, const ushort* __restrict__ BT,
               const float* __restrict__ bias, void* __restrict__ Cout,
               int M, int N, int K) {
    __shared__ ushort As[128 * 64];
    __shared__ ushort Bs[128 * 64];
    const int tid = threadIdx.x;
    const int lane = tid & 63, wid = tid >> 6;
    const int lr = lane & 15, lg = lane >> 4;
    const int wm = wid >> 1, wn = wid & 1;
    const int rowBase = blockIdx.y * 128, colBase = blockIdx.x * 128;
    const int l8 = lane >> 3;
    const int lchunk = (lane & 7) ^ l8;

    f32x4 acc[4][4];
    #pragma unroll
    for (int i = 0; i < 4; ++i)
        #pragma unroll
        for (int j = 0; j < 4; ++j)
            #pragma unroll
            for (int c = 0; c < 4; ++c) acc[i][j][c] = 0.f;

    for (int k0 = 0; k0 < K; k0 += 64) {
        #pragma unroll
        for (int i = 0; i < 4; ++i) {
            const int r = wid * 32 + i * 8;
            gl_lds16(&A[(size_t)(rowBase + r + l8) * K + k0 + lchunk * 8],
                     &As[r * 64]);
            gl_lds16(&BT[(size_t)(colBase + r + l8) * K + k0 + lchunk * 8],
                     &Bs[r * 64]);
        }
        __syncthreads();
        #pragma unroll
        for (int s = 0; s < 2; ++s) {
            short8 af[4], bf[4];
            #pragma unroll
            for (int mt = 0; mt < 4; ++mt) {
                const int r = wm * 64 + mt * 16 + lr;
                af[mt] = *reinterpret_cast<const short8*>(
                    &As[r * 64 + ((s * 4 + lg) ^ (r & 7)) * 8]);
            }
            #pragma unroll
            for (int nt = 0; nt < 4; ++nt) {
                const int r = wn * 64 + nt * 16 + lr;
                bf[nt] = *reinterpret_cast<const short8*>(
                    &Bs[r * 64 + ((s * 4 + lg) ^ (r & 7)) * 8]);
            }
            #pragma unroll
            for (int mt = 0; mt < 4; ++mt)
                #pragma unroll
                for (int nt = 0; nt < 4; ++nt)
                    acc[mt][nt] = __builtin_amdgcn_mfma_f32_16x16x32_bf16(
                        bf[nt], af[mt], acc[mt][nt], 0, 0, 0);
        }
        __syncthreads();
    }

    #pragma unroll
    for (int nt = 0; nt < 4; ++nt) {
        const int c0 = colBase + wn * 64 + nt * 16 + lg * 4;
        const float4 bv = *reinterpret_cast<const float4*>(&bias[c0]);
        const float qs = (MODE == 1 && c0 < DIM_C) ? QSCALE : 1.f;
        #pragma unroll
        for (int mt = 0; mt < 4; ++mt) {
            const int row = rowBase + wm * 64 + mt * 16 + lr;
            if (MODE == 0) {
                float4 o;
                o.x = acc[mt][nt][0] + bv.x; o.y = acc[mt][nt][1] + bv.y;
                o.z = acc[mt][nt][2] + bv.z; o.w = acc[mt][nt][3] + bv.w;
                *reinterpret_cast<float4*>(
                    &reinterpret_cast<float*>(Cout)[(size_t)row * N + c0]) = o;
            } else {
                uint2 o;
                o.x = cvt_pk_bf16((acc[mt][nt][0] + bv.x) * qs,
                                  (acc[mt][nt][1] + bv.y) * qs);
                o.y = cvt_pk_bf16((acc[mt][nt][2] + bv.z) * qs,
                                  (acc[mt][nt][3] + bv.w) * qs);
                *reinterpret_cast<uint2*>(
                    &reinterpret_cast<ushort*>(Cout)[(size_t)row * N + c0]) = o;
            }
        }
    }
}

// ---------------------------------------------------------------------------
// Flash attention v6 = proven v5b math with QBLK=64 / 4 waves / 256 threads.
// LDS 40KB -> 4 blocks/CU; grid 1024 -> exactly 4/CU = 32 waves/CU (was 16).
// Per-wave per-tile work identical to the passing kernel; only wid range,
// q0, stage row mapping, and Ps wave count change.
// ---------------------------------------------------------------------------
__global__ __launch_bounds__(256)
void flash_attn6(const ushort* __restrict__ qkvb, const ushort* __restrict__ vt,
                 ushort* __restrict__ aoutb) {
    __shared__ ushort Ks[2][64 * 64];   // 16 KB, [k][d] chunk-swizzled
    __shared__ ushort Vs[2][64 * 64];   // 16 KB, [d][k] chunk-swizzled
    __shared__ ushort Ps[4 * 16 * 64];  //  8 KB, per-wave P^T tile

    const int tid = threadIdx.x;
    const int lane = tid & 63, wid = tid >> 6;      // 4 waves
    const int lr = lane & 15, lg = lane >> 4;
    const int qt = blockIdx.x, bh = blockIdx.y;
    const int b = bh >> 3, h = bh & 7;
    const int q0 = qt * 64;
    const int l8 = lane >> 3;
    const int lchunk = (lane & 7) ^ l8;
    const int rsw = (lr & 7) ^ ((lr >> 3) << 2);    // Ps row chunk-swizzle

    // Q fragments (pre-scaled by QSCALE); B operand (col=lr=q-row)
    short8 qf[2];
    {
        const size_t qrow = (size_t)b * SEQ + q0 + wid * 16 + lr;
        #pragma unroll
        for (int s = 0; s < 2; ++s)
            qf[s] = *reinterpret_cast<const short8*>(
                &qkvb[qrow * 1536 + h * 64 + s * 32 + lg * 8]);
    }

    float m = -1e30f, l = 0.f;                      // per-lane: row q=lr
    f32x4 oa[4];
    #pragma unroll
    for (int dt = 0; dt < 4; ++dt)
        #pragma unroll
        for (int c = 0; c < 4; ++c) oa[dt][c] = 0.f;

    auto stage = [&](int kt, int buf) {
        const int k0 = kt * 64;
        #pragma unroll
        for (int i = 0; i < 2; ++i) {
            const int r = wid * 16 + i * 8;         // 4 waves x 16 rows = 64
            gl_lds16(&qkvb[(size_t)(b * SEQ + k0 + r + l8) * 1536 + DIM_C +
                           h * 64 + lchunk * 8],
                     &Ks[buf][r * 64]);
            gl_lds16(&vt[((size_t)bh * 64 + r + l8) * SEQ + k0 + lchunk * 8],
                     &Vs[buf][r * 64]);
        }
    };

    stage(0, 0);
    const int NT = SEQ / 64;
    for (int kt = 0; kt < NT; ++kt) {
        const int buf = kt & 1;
        __syncthreads();                            // stage(kt) complete
        if (kt + 1 < NT) stage(kt + 1, buf ^ 1);    // prefetch overlaps compute

        // ---- S^T = K @ Q^T (swapped operands) ----
        f32x4 sa[4];
        #pragma unroll
        for (int t = 0; t < 4; ++t)
            #pragma unroll
            for (int c = 0; c < 4; ++c) sa[t][c] = 0.f;
        __builtin_amdgcn_s_setprio(1);
        #pragma unroll
        for (int t = 0; t < 4; ++t) {
            const int n = t * 16 + lr;
            #pragma unroll
            for (int s = 0; s < 2; ++s) {
                const short8 kf = *reinterpret_cast<const short8*>(
                    &Ks[buf][n * 64 + ((s * 4 + lg) ^ (n & 7)) * 8]);
                sa[t] = __builtin_amdgcn_mfma_f32_16x16x32_bf16(
                    kf, qf[s], sa[t], 0, 0, 0);
            }
        }
        __builtin_amdgcn_s_setprio(0);

        // ---- per-lane row softmax (log2 domain), defer-max THR=8 ----
        float mx = sa[0][0];
        #pragma unroll
        for (int t = 0; t < 4; ++t)
            #pragma unroll
            for (int r = 0; r < 4; ++r) mx = fmaxf(mx, sa[t][r]);
        mx = fmaxf(mx, __shfl_xor(mx, 16));
        mx = fmaxf(mx, __shfl_xor(mx, 32));
        if (__any(mx > m + 8.f)) {                  // rare, wave-uniform
            const float mnew = fmaxf(m, mx);
            const float alpha = exp2f(m - mnew);
            m = mnew;
            l *= alpha;
            const float a0 = __shfl(alpha, lg * 4 + 0);
            const float a1 = __shfl(alpha, lg * 4 + 1);
            const float a2 = __shfl(alpha, lg * 4 + 2);
            const float a3 = __shfl(alpha, lg * 4 + 3);
            #pragma unroll
            for (int dt = 0; dt < 4; ++dt) {
                oa[dt][0] *= a0; oa[dt][1] *= a1;
                oa[dt][2] *= a2; oa[dt][3] *= a3;
            }
        }
        float sum = 0.f;
        #pragma unroll
        for (int t = 0; t < 4; ++t)
            #pragma unroll
            for (int r = 0; r < 4; ++r) {
                sa[t][r] = exp2f(sa[t][r] - m);
                sum += sa[t][r];
            }
        sum += __shfl_xor(sum, 16);
        sum += __shfl_xor(sum, 32);
        l += sum;

        // ---- P^T -> Ps row lr: 4x ds_write_b64 ----
        const int pb = wid * (16 * 64);
        const int pbase = pb + lr * 64 + (lg & 1) * 4;
        #pragma unroll
        for (int t = 0; t < 4; ++t) {
            const int chunk = (2 * t + (lg >> 1)) ^ rsw;
            uint2 w;
            w.x = cvt_pk_bf16(sa[t][0], sa[t][1]);
            w.y = cvt_pk_bf16(sa[t][2], sa[t][3]);
            *reinterpret_cast<uint2*>(&Ps[pbase + chunk * 8]) = w;
        }

        short8 pf[2];
        #pragma unroll
        for (int s = 0; s < 2; ++s)
            pf[s] = *reinterpret_cast<const short8*>(
                &Ps[pb + lr * 64 + ((lg + 4 * s) ^ rsw) * 8]);

        // ---- O += P @ V ----
        __builtin_amdgcn_s_setprio(1);
        #pragma unroll
        for (int dt = 0; dt < 4; ++dt) {
            const int d = dt * 16 + lr;
            #pragma unroll
            for (int s = 0; s < 2; ++s) {
                const short8 vf = *reinterpret_cast<const short8*>(
                    &Vs[buf][d * 64 + ((s * 4 + lg) ^ (d & 7)) * 8]);
                oa[dt] = __builtin_amdgcn_mfma_f32_16x16x32_bf16(
                    pf[s], vf, oa[dt], 0, 0, 0);
            }
        }
        __builtin_amdgcn_s_setprio(0);
    }

    // ---- normalize (broadcast per-row 1/l), write bf16 [B*N, C] ----
    const float linv = 1.f / l;
    const float v0 = __shfl(linv, lg * 4 + 0);
    const float v1 = __shfl(linv, lg * 4 + 1);
    const float v2 = __shfl(linv, lg * 4 + 2);
    const float v3 = __shfl(linv, lg * 4 + 3);
    const size_t orow0 = (size_t)b * SEQ + q0 + wid * 16;
    #pragma unroll
    for (int dt = 0; dt < 4; ++dt) {
        const int c = h * HD + dt * 16 + lr;
        aoutb[(orow0 + lg * 4 + 0) * DIM_C + c] = f2bf(oa[dt][0] * v0);
        aoutb[(orow0 + lg * 4 + 1) * DIM_C + c] = f2bf(oa[dt][1] * v1);
        aoutb[(orow0 + lg * 4 + 2) * DIM_C + c] = f2bf(oa[dt][2] * v2);
        aoutb[(orow0 + lg * 4 + 3) * DIM_C + c] = f2bf(oa[dt][3] * v3);
    }
}

// ---------------------------------------------------------------------------
extern "C" void kernel_launch(void* const* d_in, const int* in_sizes, int n_in,
                              void* d_out, int out_size, void* d_ws, size_t ws_size,
                              hipStream_t stream) {
    const float* x      = (const float*)d_in[0];
    const float* w_qkv  = (const float*)d_in[1];
    const float* b_qkv  = (const float*)d_in[2];
    const float* w_proj = (const float*)d_in[3];
    const float* b_proj = (const float*)d_in[4];
    float* out = (float*)d_out;

    const int M = BATCH * SEQ;                               // 8192
    ushort* xb     = (ushort*)d_ws;
    ushort* wqkvT  = xb     + (size_t)M * DIM_C;
    ushort* wprojT = wqkvT  + (size_t)3 * DIM_C * DIM_C;
    ushort* qkvb   = wprojT + (size_t)DIM_C * DIM_C;
    ushort* vt     = qkvb   + (size_t)M * 3 * DIM_C;
    ushort* aoutb  = vt     + (size_t)16 * HD * SEQ;

    convert_bf16<<<2048, 256, 0, stream>>>(x, xb, M * DIM_C / 4);
    transpose_w_bf16<<<dim3(3 * DIM_C / 64, DIM_C / 64), 256, 0, stream>>>(
        w_qkv, wqkvT, DIM_C, 3 * DIM_C);
    transpose_w_bf16<<<dim3(DIM_C / 64, DIM_C / 64), 256, 0, stream>>>(
        w_proj, wprojT, DIM_C, DIM_C);

    // QKV projection (Q scaled; V lands in qkvb, coalesced ushort4)
    gemm_mfma<1><<<dim3(3 * DIM_C / 128, M / 128), 256, 0, stream>>>(
        xb, wqkvT, b_qkv, qkvb, M, 3 * DIM_C, DIM_C);

    transpose_v<<<dim3(SEQ / 64, BATCH * HEADS), 256, 0, stream>>>(qkvb, vt);

    flash_attn6<<<dim3(SEQ / 64, BATCH * HEADS), 256, 0, stream>>>(
        qkvb, vt, aoutb);

    gemm_mfma<0><<<dim3(DIM_C / 128, M / 128), 256, 0, stream>>>(
        aoutb, wprojT, b_proj, out, M, DIM_C, DIM_C);
}

// Round 10
// 251.181 us; speedup vs baseline: 1.0701x; 1.0701x over previous
//
#include <hip/hip_runtime.h>

#define DIM_C 512
#define HEADS 8
#define HD 64
#define BATCH 2
#define SEQ 4096
#define QSCALE (0.125f * 1.44269504088896f)   // 1/sqrt(64) * log2(e)

typedef __attribute__((ext_vector_type(8))) short short8;
typedef __attribute__((ext_vector_type(4))) float f32x4;

// fp32 -> bf16 round-to-nearest-even
__device__ __forceinline__ ushort f2bf(float f) {
    union { float f; unsigned u; } x; x.f = f;
    unsigned r = x.u + 0x7fffu + ((x.u >> 16) & 1u);
    return (ushort)(r >> 16);
}

// async global->LDS, 16B per lane. LDS dest = wave-uniform base + lane*16.
__device__ __forceinline__ void gl_lds16(const void* g, void* l) {
    __builtin_amdgcn_global_load_lds(
        (const __attribute__((address_space(1))) unsigned int*)g,
        (__attribute__((address_space(3))) unsigned int*)l, 16, 0, 0);
}

__device__ __forceinline__ unsigned cvt_pk_bf16(float lo, float hi) {
    unsigned w;
    asm("v_cvt_pk_bf16_f32 %0, %1, %2" : "=v"(w) : "v"(lo), "v"(hi));
    return w;
}

// ---------------------------------------------------------------------------
// prep kernels (proven)
// ---------------------------------------------------------------------------
__global__ __launch_bounds__(256)
void convert_bf16(const float* __restrict__ in, ushort* __restrict__ out, int n4) {
    int i = blockIdx.x * blockDim.x + threadIdx.x;
    const int stride = gridDim.x * blockDim.x;
    for (; i < n4; i += stride) {
        const float4 v = reinterpret_cast<const float4*>(in)[i];
        ushort4 o;
        o.x = f2bf(v.x); o.y = f2bf(v.y); o.z = f2bf(v.z); o.w = f2bf(v.w);
        reinterpret_cast<ushort4*>(out)[i] = o;
    }
}

__global__ __launch_bounds__(256)
void transpose_w_bf16(const float* __restrict__ in, ushort* __restrict__ out,
                      int R, int C) {
    __shared__ ushort Ls[64 * 68];
    const int tid = threadIdx.x;
    const int c0 = blockIdx.x * 64, r0 = blockIdx.y * 64;
    #pragma unroll
    for (int p = 0; p < 4; ++p) {
        const int idx = tid + p * 256;
        const int r = idx >> 4, c4 = (idx & 15) * 4;
        const float4 v = *reinterpret_cast<const float4*>(
            &in[(size_t)(r0 + r) * C + c0 + c4]);
        ushort4 o; o.x = f2bf(v.x); o.y = f2bf(v.y); o.z = f2bf(v.z); o.w = f2bf(v.w);
        *reinterpret_cast<ushort4*>(&Ls[r * 68 + c4]) = o;
    }
    __syncthreads();
    #pragma unroll
    for (int p = 0; p < 4; ++p) {
        const int idx = tid + p * 256;
        const int c = idx >> 4, r4 = (idx & 15) * 4;
        ushort4 o;
        o.x = Ls[(r4 + 0) * 68 + c]; o.y = Ls[(r4 + 1) * 68 + c];
        o.z = Ls[(r4 + 2) * 68 + c]; o.w = Ls[(r4 + 3) * 68 + c];
        *reinterpret_cast<ushort4*>(&out[(size_t)(c0 + c) * R + r0 + r4]) = o;
    }
}

// V extract+transpose: qkvb [B*N,1536] cols 1024.. -> vt[bh][d=64][n=4096]
__global__ __launch_bounds__(256)
void transpose_v(const ushort* __restrict__ qkvb, ushort* __restrict__ vt) {
    __shared__ ushort Ls[64 * 68];
    const int tid = threadIdx.x;
    const int n0 = blockIdx.x * 64;
    const int bh = blockIdx.y, b = bh >> 3, h = bh & 7;
    #pragma unroll
    for (int p = 0; p < 4; ++p) {
        const int idx = tid + p * 256;
        const int r = idx >> 4, c4 = (idx & 15) * 4;
        const ushort4 v = *reinterpret_cast<const ushort4*>(
            &qkvb[(size_t)(b * SEQ + n0 + r) * 1536 + 1024 + h * 64 + c4]);
        *reinterpret_cast<ushort4*>(&Ls[r * 68 + c4]) = v;
    }
    __syncthreads();
    #pragma unroll
    for (int p = 0; p < 4; ++p) {
        const int idx = tid + p * 256;
        const int d = idx >> 4, n4 = (idx & 15) * 4;
        ushort4 o;
        o.x = Ls[(n4 + 0) * 68 + d]; o.y = Ls[(n4 + 1) * 68 + d];
        o.z = Ls[(n4 + 2) * 68 + d]; o.w = Ls[(n4 + 3) * 68 + d];
        *reinterpret_cast<ushort4*>(&vt[((size_t)bh * 64 + d) * SEQ + n0 + n4]) = o;
    }
}

// ---------------------------------------------------------------------------
// bf16 MFMA GEMM, swapped operands (lane = one C-row, 4 consecutive cols).
// MODE 0: float4 out. MODE 1: ushort4 out, Q cols scaled by QSCALE.
// ---------------------------------------------------------------------------
template<int MODE>
__global__ __launch_bounds__(256)
void gemm_mfma(const ushort* __restrict__ A, const ushort* __restrict__ BT,
               const float* __restrict__ bias, void* __restrict__ Cout,
               int M, int N, int K) {
    __shared__ ushort As[128 * 64];
    __shared__ ushort Bs[128 * 64];
    const int tid = threadIdx.x;
    const int lane = tid & 63, wid = tid >> 6;
    const int lr = lane & 15, lg = lane >> 4;
    const int wm = wid >> 1, wn = wid & 1;
    const int rowBase = blockIdx.y * 128, colBase = blockIdx.x * 128;
    const int l8 = lane >> 3;
    const int lchunk = (lane & 7) ^ l8;

    f32x4 acc[4][4];
    #pragma unroll
    for (int i = 0; i < 4; ++i)
        #pragma unroll
        for (int j = 0; j < 4; ++j)
            #pragma unroll
            for (int c = 0; c < 4; ++c) acc[i][j][c] = 0.f;

    for (int k0 = 0; k0 < K; k0 += 64) {
        #pragma unroll
        for (int i = 0; i < 4; ++i) {
            const int r = wid * 32 + i * 8;
            gl_lds16(&A[(size_t)(rowBase + r + l8) * K + k0 + lchunk * 8],
                     &As[r * 64]);
            gl_lds16(&BT[(size_t)(colBase + r + l8) * K + k0 + lchunk * 8],
                     &Bs[r * 64]);
        }
        __syncthreads();
        #pragma unroll
        for (int s = 0; s < 2; ++s) {
            short8 af[4], bf[4];
            #pragma unroll
            for (int mt = 0; mt < 4; ++mt) {
                const int r = wm * 64 + mt * 16 + lr;
                af[mt] = *reinterpret_cast<const short8*>(
                    &As[r * 64 + ((s * 4 + lg) ^ (r & 7)) * 8]);
            }
            #pragma unroll
            for (int nt = 0; nt < 4; ++nt) {
                const int r = wn * 64 + nt * 16 + lr;
                bf[nt] = *reinterpret_cast<const short8*>(
                    &Bs[r * 64 + ((s * 4 + lg) ^ (r & 7)) * 8]);
            }
            #pragma unroll
            for (int mt = 0; mt < 4; ++mt)
                #pragma unroll
                for (int nt = 0; nt < 4; ++nt)
                    acc[mt][nt] = __builtin_amdgcn_mfma_f32_16x16x32_bf16(
                        bf[nt], af[mt], acc[mt][nt], 0, 0, 0);
        }
        __syncthreads();
    }

    #pragma unroll
    for (int nt = 0; nt < 4; ++nt) {
        const int c0 = colBase + wn * 64 + nt * 16 + lg * 4;
        const float4 bv = *reinterpret_cast<const float4*>(&bias[c0]);
        const float qs = (MODE == 1 && c0 < DIM_C) ? QSCALE : 1.f;
        #pragma unroll
        for (int mt = 0; mt < 4; ++mt) {
            const int row = rowBase + wm * 64 + mt * 16 + lr;
            if (MODE == 0) {
                float4 o;
                o.x = acc[mt][nt][0] + bv.x; o.y = acc[mt][nt][1] + bv.y;
                o.z = acc[mt][nt][2] + bv.z; o.w = acc[mt][nt][3] + bv.w;
                *reinterpret_cast<float4*>(
                    &reinterpret_cast<float*>(Cout)[(size_t)row * N + c0]) = o;
            } else {
                uint2 o;
                o.x = cvt_pk_bf16((acc[mt][nt][0] + bv.x) * qs,
                                  (acc[mt][nt][1] + bv.y) * qs);
                o.y = cvt_pk_bf16((acc[mt][nt][2] + bv.z) * qs,
                                  (acc[mt][nt][3] + bv.w) * qs);
                *reinterpret_cast<uint2*>(
                    &reinterpret_cast<ushort*>(Cout)[(size_t)row * N + c0]) = o;
            }
        }
    }
}

// ---------------------------------------------------------------------------
// Flash attention v7 = round-8 v5b structure (QBLK=128, 8 waves, proven
// 150us) + two VALU cuts:
//   (a) l via MFMA-ones: lacc = mfma(ones, pf, lacc) accumulates
//       Sum_k P[k][q=lr] on the matrix pipe; replaces 16 v_add + 2 shfl.
//       lacc never zeroed; scaled by alpha on the rare rescale (per-lane,
//       no shfl). Final l = lacc[0].
//   (b) row-max as v_max3 triples (15 -> 8 ops).
// All layouts/addresses byte-identical to the passing round-8 kernel.
// ---------------------------------------------------------------------------
__global__ __launch_bounds__(512)
void flash_attn7(const ushort* __restrict__ qkvb, const ushort* __restrict__ vt,
                 ushort* __restrict__ aoutb) {
    __shared__ ushort Ks[2][64 * 64];   // [k][d] chunk-swizzled
    __shared__ ushort Vs[2][64 * 64];   // [d][k] chunk-swizzled
    __shared__ ushort Ps[8 * 16 * 64];  // per-wave P^T tile

    const int tid = threadIdx.x;
    const int lane = tid & 63, wid = tid >> 6;      // 8 waves
    const int lr = lane & 15, lg = lane >> 4;
    const int qt = blockIdx.x, bh = blockIdx.y;
    const int b = bh >> 3, h = bh & 7;
    const int q0 = qt * 128;
    const int l8 = lane >> 3;
    const int lchunk = (lane & 7) ^ l8;
    const int rsw = (lr & 7) ^ ((lr >> 3) << 2);    // Ps row chunk-swizzle

    // bf16 1.0 x8 fragment for the l-sum MFMA
    short8 onesf;
    #pragma unroll
    for (int i = 0; i < 8; ++i) onesf[i] = (short)0x3F80;

    // Q fragments (pre-scaled by QSCALE); B operand (col=lr=q-row)
    short8 qf[2];
    {
        const size_t qrow = (size_t)b * SEQ + q0 + wid * 16 + lr;
        #pragma unroll
        for (int s = 0; s < 2; ++s)
            qf[s] = *reinterpret_cast<const short8*>(
                &qkvb[qrow * 1536 + h * 64 + s * 32 + lg * 8]);
    }

    float m = -1e30f;                               // per-lane: row q=lr
    f32x4 lacc;                                     // l accumulator (row q=lr)
    lacc[0] = 0.f; lacc[1] = 0.f; lacc[2] = 0.f; lacc[3] = 0.f;
    f32x4 oa[4];
    #pragma unroll
    for (int dt = 0; dt < 4; ++dt)
        #pragma unroll
        for (int c = 0; c < 4; ++c) oa[dt][c] = 0.f;

    auto stage = [&](int kt, int buf) {
        const int k0 = kt * 64;
        const int r = wid * 8;                      // 8 waves x 8 rows = 64
        gl_lds16(&qkvb[(size_t)(b * SEQ + k0 + r + l8) * 1536 + DIM_C +
                       h * 64 + lchunk * 8],
                 &Ks[buf][r * 64]);
        gl_lds16(&vt[((size_t)bh * 64 + r + l8) * SEQ + k0 + lchunk * 8],
                 &Vs[buf][r * 64]);
    };

    stage(0, 0);
    const int NT = SEQ / 64;
    for (int kt = 0; kt < NT; ++kt) {
        const int buf = kt & 1;
        __syncthreads();                            // stage(kt) complete
        if (kt + 1 < NT) stage(kt + 1, buf ^ 1);    // prefetch overlaps compute

        // ---- S^T = K @ Q^T (swapped operands) ----
        f32x4 sa[4];
        #pragma unroll
        for (int t = 0; t < 4; ++t)
            #pragma unroll
            for (int c = 0; c < 4; ++c) sa[t][c] = 0.f;
        __builtin_amdgcn_s_setprio(1);
        #pragma unroll
        for (int t = 0; t < 4; ++t) {
            const int n = t * 16 + lr;
            #pragma unroll
            for (int s = 0; s < 2; ++s) {
                const short8 kf = *reinterpret_cast<const short8*>(
                    &Ks[buf][n * 64 + ((s * 4 + lg) ^ (n & 7)) * 8]);
                sa[t] = __builtin_amdgcn_mfma_f32_16x16x32_bf16(
                    kf, qf[s], sa[t], 0, 0, 0);
            }
        }
        __builtin_amdgcn_s_setprio(0);

        // ---- per-lane row max (v_max3 triples), defer-max THR=8 ----
        float mx = fmaxf(fmaxf(sa[0][0], sa[0][1]), sa[0][2]);
        mx = fmaxf(fmaxf(mx, sa[0][3]), sa[1][0]);
        mx = fmaxf(fmaxf(mx, sa[1][1]), sa[1][2]);
        mx = fmaxf(fmaxf(mx, sa[1][3]), sa[2][0]);
        mx = fmaxf(fmaxf(mx, sa[2][1]), sa[2][2]);
        mx = fmaxf(fmaxf(mx, sa[2][3]), sa[3][0]);
        mx = fmaxf(fmaxf(mx, sa[3][1]), sa[3][2]);
        mx = fmaxf(mx, sa[3][3]);
        mx = fmaxf(mx, __shfl_xor(mx, 16));
        mx = fmaxf(mx, __shfl_xor(mx, 32));
        if (__any(mx > m + 8.f)) {                  // rare, wave-uniform
            const float mnew = fmaxf(m, mx);
            const float alpha = exp2f(m - mnew);
            m = mnew;
            lacc[0] *= alpha; lacc[1] *= alpha;
            lacc[2] *= alpha; lacc[3] *= alpha;
            const float a0 = __shfl(alpha, lg * 4 + 0);
            const float a1 = __shfl(alpha, lg * 4 + 1);
            const float a2 = __shfl(alpha, lg * 4 + 2);
            const float a3 = __shfl(alpha, lg * 4 + 3);
            #pragma unroll
            for (int dt = 0; dt < 4; ++dt) {
                oa[dt][0] *= a0; oa[dt][1] *= a1;
                oa[dt][2] *= a2; oa[dt][3] *= a3;
            }
        }
        #pragma unroll
        for (int t = 0; t < 4; ++t)
            #pragma unroll
            for (int r = 0; r < 4; ++r)
                sa[t][r] = exp2f(sa[t][r] - m);

        // ---- P^T -> Ps row lr: 4x ds_write_b64 ----
        const int pb = wid * (16 * 64);
        const int pbase = pb + lr * 64 + (lg & 1) * 4;
        #pragma unroll
        for (int t = 0; t < 4; ++t) {
            const int chunk = (2 * t + (lg >> 1)) ^ rsw;
            uint2 w;
            w.x = cvt_pk_bf16(sa[t][0], sa[t][1]);
            w.y = cvt_pk_bf16(sa[t][2], sa[t][3]);
            *reinterpret_cast<uint2*>(&Ps[pbase + chunk * 8]) = w;
        }

        short8 pf[2];
        #pragma unroll
        for (int s = 0; s < 2; ++s)
            pf[s] = *reinterpret_cast<const short8*>(
                &Ps[pb + lr * 64 + ((lg + 4 * s) ^ rsw) * 8]);

        // ---- O += P @ V ; l += ones @ P^T (matrix pipe) ----
        __builtin_amdgcn_s_setprio(1);
        #pragma unroll
        for (int s = 0; s < 2; ++s)
            lacc = __builtin_amdgcn_mfma_f32_16x16x32_bf16(
                onesf, pf[s], lacc, 0, 0, 0);
        #pragma unroll
        for (int dt = 0; dt < 4; ++dt) {
            const int d = dt * 16 + lr;
            #pragma unroll
            for (int s = 0; s < 2; ++s) {
                const short8 vf = *reinterpret_cast<const short8*>(
                    &Vs[buf][d * 64 + ((s * 4 + lg) ^ (d & 7)) * 8]);
                oa[dt] = __builtin_amdgcn_mfma_f32_16x16x32_bf16(
                    pf[s], vf, oa[dt], 0, 0, 0);
            }
        }
        __builtin_amdgcn_s_setprio(0);
    }

    // ---- normalize (broadcast per-row 1/l), write bf16 [B*N, C] ----
    const float linv = 1.f / lacc[0];
    const float v0 = __shfl(linv, lg * 4 + 0);
    const float v1 = __shfl(linv, lg * 4 + 1);
    const float v2 = __shfl(linv, lg * 4 + 2);
    const float v3 = __shfl(linv, lg * 4 + 3);
    const size_t orow0 = (size_t)b * SEQ + q0 + wid * 16;
    #pragma unroll
    for (int dt = 0; dt < 4; ++dt) {
        const int c = h * HD + dt * 16 + lr;
        aoutb[(orow0 + lg * 4 + 0) * DIM_C + c] = f2bf(oa[dt][0] * v0);
        aoutb[(orow0 + lg * 4 + 1) * DIM_C + c] = f2bf(oa[dt][1] * v1);
        aoutb[(orow0 + lg * 4 + 2) * DIM_C + c] = f2bf(oa[dt][2] * v2);
        aoutb[(orow0 + lg * 4 + 3) * DIM_C + c] = f2bf(oa[dt][3] * v3);
    }
}

// ---------------------------------------------------------------------------
extern "C" void kernel_launch(void* const* d_in, const int* in_sizes, int n_in,
                              void* d_out, int out_size, void* d_ws, size_t ws_size,
                              hipStream_t stream) {
    const float* x      = (const float*)d_in[0];
    const float* w_qkv  = (const float*)d_in[1];
    const float* b_qkv  = (const float*)d_in[2];
    const float* w_proj = (const float*)d_in[3];
    const float* b_proj = (const float*)d_in[4];
    float* out = (float*)d_out;

    const int M = BATCH * SEQ;                               // 8192
    ushort* xb     = (ushort*)d_ws;
    ushort* wqkvT  = xb     + (size_t)M * DIM_C;
    ushort* wprojT = wqkvT  + (size_t)3 * DIM_C * DIM_C;
    ushort* qkvb   = wprojT + (size_t)DIM_C * DIM_C;
    ushort* vt     = qkvb   + (size_t)M * 3 * DIM_C;
    ushort* aoutb  = vt     + (size_t)16 * HD * SEQ;

    convert_bf16<<<2048, 256, 0, stream>>>(x, xb, M * DIM_C / 4);
    transpose_w_bf16<<<dim3(3 * DIM_C / 64, DIM_C / 64), 256, 0, stream>>>(
        w_qkv, wqkvT, DIM_C, 3 * DIM_C);
    transpose_w_bf16<<<dim3(DIM_C / 64, DIM_C / 64), 256, 0, stream>>>(
        w_proj, wprojT, DIM_C, DIM_C);

    // QKV projection (Q scaled; V lands in qkvb, coalesced ushort4)
    gemm_mfma<1><<<dim3(3 * DIM_C / 128, M / 128), 256, 0, stream>>>(
        xb, wqkvT, b_qkv, qkvb, M, 3 * DIM_C, DIM_C);

    transpose_v<<<dim3(SEQ / 64, BATCH * HEADS), 256, 0, stream>>>(qkvb, vt);

    flash_attn7<<<dim3(SEQ / 128, BATCH * HEADS), 512, 0, stream>>>(
        qkvb, vt, aoutb);

    gemm_mfma<0><<<dim3(DIM_C / 128, M / 128), 256, 0, stream>>>(
        aoutb, wprojT, b_proj, out, M, DIM_C, DIM_C);
}

// Round 12
// 243.010 us; speedup vs baseline: 1.1061x; 1.0336x over previous
//
#include <hip/hip_runtime.h>

#define DIM_C 512
#define HEADS 8
#define HD 64
#define BATCH 2
#define SEQ 4096
#define QSCALE (0.125f * 1.44269504088896f)   // 1/sqrt(64) * log2(e)

typedef __attribute__((ext_vector_type(8))) short short8;
typedef __attribute__((ext_vector_type(4))) float f32x4;

// fp32 -> bf16 round-to-nearest-even
__device__ __forceinline__ ushort f2bf(float f) {
    union { float f; unsigned u; } x; x.f = f;
    unsigned r = x.u + 0x7fffu + ((x.u >> 16) & 1u);
    return (ushort)(r >> 16);
}

// async global->LDS, 16B per lane. LDS dest = wave-uniform base + lane*16.
__device__ __forceinline__ void gl_lds16(const void* g, void* l) {
    __builtin_amdgcn_global_load_lds(
        (const __attribute__((address_space(1))) unsigned int*)g,
        (__attribute__((address_space(3))) unsigned int*)l, 16, 0, 0);
}

__device__ __forceinline__ unsigned cvt_pk_bf16(float lo, float hi) {
    unsigned w;
    asm("v_cvt_pk_bf16_f32 %0, %1, %2" : "=v"(w) : "v"(lo), "v"(hi));
    return w;
}

// ---------------------------------------------------------------------------
// prep kernels (proven)
// ---------------------------------------------------------------------------
__global__ __launch_bounds__(256)
void convert_bf16(const float* __restrict__ in, ushort* __restrict__ out, int n4) {
    int i = blockIdx.x * blockDim.x + threadIdx.x;
    const int stride = gridDim.x * blockDim.x;
    for (; i < n4; i += stride) {
        const float4 v = reinterpret_cast<const float4*>(in)[i];
        ushort4 o;
        o.x = f2bf(v.x); o.y = f2bf(v.y); o.z = f2bf(v.z); o.w = f2bf(v.w);
        reinterpret_cast<ushort4*>(out)[i] = o;
    }
}

__global__ __launch_bounds__(256)
void transpose_w_bf16(const float* __restrict__ in, ushort* __restrict__ out,
                      int R, int C) {
    __shared__ ushort Ls[64 * 68];
    const int tid = threadIdx.x;
    const int c0 = blockIdx.x * 64, r0 = blockIdx.y * 64;
    #pragma unroll
    for (int p = 0; p < 4; ++p) {
        const int idx = tid + p * 256;
        const int r = idx >> 4, c4 = (idx & 15) * 4;
        const float4 v = *reinterpret_cast<const float4*>(
            &in[(size_t)(r0 + r) * C + c0 + c4]);
        ushort4 o; o.x = f2bf(v.x); o.y = f2bf(v.y); o.z = f2bf(v.z); o.w = f2bf(v.w);
        *reinterpret_cast<ushort4*>(&Ls[r * 68 + c4]) = o;
    }
    __syncthreads();
    #pragma unroll
    for (int p = 0; p < 4; ++p) {
        const int idx = tid + p * 256;
        const int c = idx >> 4, r4 = (idx & 15) * 4;
        ushort4 o;
        o.x = Ls[(r4 + 0) * 68 + c]; o.y = Ls[(r4 + 1) * 68 + c];
        o.z = Ls[(r4 + 2) * 68 + c]; o.w = Ls[(r4 + 3) * 68 + c];
        *reinterpret_cast<ushort4*>(&out[(size_t)(c0 + c) * R + r0 + r4]) = o;
    }
}

// V extract+transpose: qkvb [B*N,1536] cols 1024.. -> vt[bh][d=64][n=4096]
__global__ __launch_bounds__(256)
void transpose_v(const ushort* __restrict__ qkvb, ushort* __restrict__ vt) {
    __shared__ ushort Ls[64 * 68];
    const int tid = threadIdx.x;
    const int n0 = blockIdx.x * 64;
    const int bh = blockIdx.y, b = bh >> 3, h = bh & 7;
    #pragma unroll
    for (int p = 0; p < 4; ++p) {
        const int idx = tid + p * 256;
        const int r = idx >> 4, c4 = (idx & 15) * 4;
        const ushort4 v = *reinterpret_cast<const ushort4*>(
            &qkvb[(size_t)(b * SEQ + n0 + r) * 1536 + 1024 + h * 64 + c4]);
        *reinterpret_cast<ushort4*>(&Ls[r * 68 + c4]) = v;
    }
    __syncthreads();
    #pragma unroll
    for (int p = 0; p < 4; ++p) {
        const int idx = tid + p * 256;
        const int d = idx >> 4, n4 = (idx & 15) * 4;
        ushort4 o;
        o.x = Ls[(n4 + 0) * 68 + d]; o.y = Ls[(n4 + 1) * 68 + d];
        o.z = Ls[(n4 + 2) * 68 + d]; o.w = Ls[(n4 + 3) * 68 + d];
        *reinterpret_cast<ushort4*>(&vt[((size_t)bh * 64 + d) * SEQ + n0 + n4]) = o;
    }
}

// ---------------------------------------------------------------------------
// bf16 MFMA GEMM — ROUND-6 PROVEN VERSION (un-swapped operands, scalar
// epilogue). Empirically ~13us faster in aggregate than the swapped variant
// (rest 91.8 vs 104.5-106.2 us across rounds 6 vs 7/8/10).
// MODE 0: fp32 out. MODE 1: bf16 out, cols<512 scaled by QSCALE.
// ---------------------------------------------------------------------------
template<int MODE>
__global__ __launch_bounds__(256)
void gemm_mfma(const ushort* __restrict__ A, const ushort* __restrict__ BT,
               const float* __restrict__ bias, void* __restrict__ Cout,
               int M, int N, int K) {
    __shared__ ushort As[128 * 64];
    __shared__ ushort Bs[128 * 64];
    const int tid = threadIdx.x;
    const int lane = tid & 63, wid = tid >> 6;
    const int lr = lane & 15, lg = lane >> 4;
    const int wm = wid >> 1, wn = wid & 1;
    const int rowBase = blockIdx.y * 128, colBase = blockIdx.x * 128;
    const int l8 = lane >> 3;
    const int lchunk = (lane & 7) ^ l8;

    f32x4 acc[4][4];
    #pragma unroll
    for (int i = 0; i < 4; ++i)
        #pragma unroll
        for (int j = 0; j < 4; ++j)
            #pragma unroll
            for (int c = 0; c < 4; ++c) acc[i][j][c] = 0.f;

    for (int k0 = 0; k0 < K; k0 += 64) {
        #pragma unroll
        for (int i = 0; i < 4; ++i) {
            const int r = wid * 32 + i * 8;
            gl_lds16(&A[(size_t)(rowBase + r + l8) * K + k0 + lchunk * 8],
                     &As[r * 64]);
            gl_lds16(&BT[(size_t)(colBase + r + l8) * K + k0 + lchunk * 8],
                     &Bs[r * 64]);
        }
        __syncthreads();
        #pragma unroll
        for (int s = 0; s < 2; ++s) {
            short8 af[4], bf[4];
            #pragma unroll
            for (int mt = 0; mt < 4; ++mt) {
                const int r = wm * 64 + mt * 16 + lr;
                af[mt] = *reinterpret_cast<const short8*>(
                    &As[r * 64 + ((s * 4 + lg) ^ (r & 7)) * 8]);
            }
            #pragma unroll
            for (int nt = 0; nt < 4; ++nt) {
                const int r = wn * 64 + nt * 16 + lr;
                bf[nt] = *reinterpret_cast<const short8*>(
                    &Bs[r * 64 + ((s * 4 + lg) ^ (r & 7)) * 8]);
            }
            #pragma unroll
            for (int mt = 0; mt < 4; ++mt)
                #pragma unroll
                for (int nt = 0; nt < 4; ++nt)
                    acc[mt][nt] = __builtin_amdgcn_mfma_f32_16x16x32_bf16(
                        af[mt], bf[nt], acc[mt][nt], 0, 0, 0);
        }
        __syncthreads();
    }

    #pragma unroll
    for (int nt = 0; nt < 4; ++nt) {
        const int col = colBase + wn * 64 + nt * 16 + lr;
        const float bv = bias[col];
        const float qs = (MODE == 1 && col < DIM_C) ? QSCALE : 1.f;
        #pragma unroll
        for (int mt = 0; mt < 4; ++mt) {
            #pragma unroll
            for (int j = 0; j < 4; ++j) {
                const int row = rowBase + wm * 64 + mt * 16 + lg * 4 + j;
                const float v = (acc[mt][nt][j] + bv) * qs;
                if (MODE == 0)
                    reinterpret_cast<float*>(Cout)[(size_t)row * N + col] = v;
                else
                    reinterpret_cast<ushort*>(Cout)[(size_t)row * N + col] = f2bf(v);
            }
        }
    }
}

// ---------------------------------------------------------------------------
// Flash attention v8 = v7 math with KVBLK=128 (half the barriers/loop iters).
//  Ks[2][128x64]: K rows double, row length 64 unchanged -> identical
//    per-row swizzle/fragment formulas (n now 0..127; (n&7) unchanged).
//  Vs[2][64x128]: row length 128 (16 chunks). Read chunk = kh*8 +
//    ((s*4+lg)^(d&7)); staging source chunk = (c16&8)|((c16&7)^(d&7)) —
//    same involution on the low 3 bits, k-half bit identity.
//  Ps reused across the two k-halves (wave-local, in-order LDS ops).
//  Per-S-element softmax/P/PV work identical to the proven v7 kernel.
// ---------------------------------------------------------------------------
__global__ __launch_bounds__(512)
void flash_attn8(const ushort* __restrict__ qkvb, const ushort* __restrict__ vt,
                 ushort* __restrict__ aoutb) {
    __shared__ ushort Ks[2][128 * 64];  // 32 KB, [k][d] chunk-swizzled
    __shared__ ushort Vs[2][64 * 128];  // 32 KB, [d][k] chunk-swizzled
    __shared__ ushort Ps[8 * 16 * 64];  // 16 KB, per-wave P^T tile (reused 2x)

    const int tid = threadIdx.x;
    const int lane = tid & 63, wid = tid >> 6;      // 8 waves
    const int lr = lane & 15, lg = lane >> 4;
    const int qt = blockIdx.x, bh = blockIdx.y;
    const int b = bh >> 3, h = bh & 7;
    const int q0 = qt * 128;
    const int l8 = lane >> 3;
    const int lchunk = (lane & 7) ^ l8;
    const int rsw = (lr & 7) ^ ((lr >> 3) << 2);    // Ps row chunk-swizzle

    // bf16 1.0 x8 fragment for the l-sum MFMA
    short8 onesf;
    #pragma unroll
    for (int i = 0; i < 8; ++i) onesf[i] = (short)0x3F80;

    // Q fragments (pre-scaled by QSCALE); B operand (col=lr=q-row)
    short8 qf[2];
    {
        const size_t qrow = (size_t)b * SEQ + q0 + wid * 16 + lr;
        #pragma unroll
        for (int s = 0; s < 2; ++s)
            qf[s] = *reinterpret_cast<const short8*>(
                &qkvb[qrow * 1536 + h * 64 + s * 32 + lg * 8]);
    }

    float m = -1e30f;                               // per-lane: row q=lr
    f32x4 lacc;
    lacc[0] = 0.f; lacc[1] = 0.f; lacc[2] = 0.f; lacc[3] = 0.f;
    f32x4 oa[4];
    #pragma unroll
    for (int dt = 0; dt < 4; ++dt)
        #pragma unroll
        for (int c = 0; c < 4; ++c) oa[dt][c] = 0.f;

    auto stage = [&](int kt, int buf) {
        const int k0 = kt * 128;
        // K: 128 rows x 64; 8 waves x 16 rows -> 2 calls of 8 rows
        #pragma unroll
        for (int i = 0; i < 2; ++i) {
            const int r = wid * 16 + i * 8;
            gl_lds16(&qkvb[(size_t)(b * SEQ + k0 + r + l8) * 1536 + DIM_C +
                           h * 64 + lchunk * 8],
                     &Ks[buf][r * 64]);
        }
        // V: 64 d-rows x 128; 8 waves x 8 rows -> 2 calls of 4 rows
        #pragma unroll
        for (int i = 0; i < 2; ++i) {
            const int d0 = wid * 8 + i * 4;
            const int d = d0 + (lane >> 4);
            const int c16 = lane & 15;
            const int gch = (c16 & 8) | ((c16 & 7) ^ (d & 7));
            gl_lds16(&vt[((size_t)bh * 64 + d) * SEQ + k0 + gch * 8],
                     &Vs[buf][d0 * 128]);
        }
    };

    stage(0, 0);
    const int NT = SEQ / 128;                       // 32 iterations
    for (int kt = 0; kt < NT; ++kt) {
        const int buf = kt & 1;
        __syncthreads();                            // stage(kt) complete
        if (kt + 1 < NT) stage(kt + 1, buf ^ 1);    // prefetch overlaps compute

        // ---- S^T = K @ Q^T over 128 k-rows ----
        f32x4 sa[8];
        #pragma unroll
        for (int t = 0; t < 8; ++t)
            #pragma unroll
            for (int c = 0; c < 4; ++c) sa[t][c] = 0.f;
        __builtin_amdgcn_s_setprio(1);
        #pragma unroll
        for (int t = 0; t < 8; ++t) {
            const int n = t * 16 + lr;
            #pragma unroll
            for (int s = 0; s < 2; ++s) {
                const short8 kf = *reinterpret_cast<const short8*>(
                    &Ks[buf][n * 64 + ((s * 4 + lg) ^ (n & 7)) * 8]);
                sa[t] = __builtin_amdgcn_mfma_f32_16x16x32_bf16(
                    kf, qf[s], sa[t], 0, 0, 0);
            }
        }
        __builtin_amdgcn_s_setprio(0);

        // ---- per-lane row max (max3 triples), defer-max THR=8 ----
        float mx = fmaxf(fmaxf(sa[0][0], sa[0][1]), sa[0][2]);
        #pragma unroll
        for (int t = 1; t < 8; ++t)
            mx = fmaxf(fmaxf(mx, sa[t][0]),
                       fmaxf(fmaxf(sa[t][1], sa[t][2]), sa[t][3]));
        mx = fmaxf(mx, sa[0][3]);
        mx = fmaxf(mx, __shfl_xor(mx, 16));
        mx = fmaxf(mx, __shfl_xor(mx, 32));
        if (__any(mx > m + 8.f)) {                  // rare, wave-uniform
            const float mnew = fmaxf(m, mx);
            const float alpha = exp2f(m - mnew);
            m = mnew;
            lacc[0] *= alpha; lacc[1] *= alpha;
            lacc[2] *= alpha; lacc[3] *= alpha;
            const float a0 = __shfl(alpha, lg * 4 + 0);
            const float a1 = __shfl(alpha, lg * 4 + 1);
            const float a2 = __shfl(alpha, lg * 4 + 2);
            const float a3 = __shfl(alpha, lg * 4 + 3);
            #pragma unroll
            for (int dt = 0; dt < 4; ++dt) {
                oa[dt][0] *= a0; oa[dt][1] *= a1;
                oa[dt][2] *= a2; oa[dt][3] *= a3;
            }
        }
        #pragma unroll
        for (int t = 0; t < 8; ++t)
            #pragma unroll
            for (int r = 0; r < 4; ++r)
                sa[t][r] = exp2f(sa[t][r] - m);

        // ---- two k-halves: pack P^T -> Ps (reused), PV + l-sum ----
        const int pb = wid * (16 * 64);
        const int pbase = pb + lr * 64 + (lg & 1) * 4;
        #pragma unroll
        for (int kh = 0; kh < 2; ++kh) {
            #pragma unroll
            for (int t = 0; t < 4; ++t) {
                const int chunk = (2 * t + (lg >> 1)) ^ rsw;
                uint2 w;
                w.x = cvt_pk_bf16(sa[kh * 4 + t][0], sa[kh * 4 + t][1]);
                w.y = cvt_pk_bf16(sa[kh * 4 + t][2], sa[kh * 4 + t][3]);
                *reinterpret_cast<uint2*>(&Ps[pbase + chunk * 8]) = w;
            }
            short8 pf[2];
            #pragma unroll
            for (int s = 0; s < 2; ++s)
                pf[s] = *reinterpret_cast<const short8*>(
                    &Ps[pb + lr * 64 + ((lg + 4 * s) ^ rsw) * 8]);

            __builtin_amdgcn_s_setprio(1);
            #pragma unroll
            for (int s = 0; s < 2; ++s)
                lacc = __builtin_amdgcn_mfma_f32_16x16x32_bf16(
                    onesf, pf[s], lacc, 0, 0, 0);
            #pragma unroll
            for (int dt = 0; dt < 4; ++dt) {
                const int d = dt * 16 + lr;
                #pragma unroll
                for (int s = 0; s < 2; ++s) {
                    const short8 vf = *reinterpret_cast<const short8*>(
                        &Vs[buf][d * 128 +
                                 (kh * 8 + ((s * 4 + lg) ^ (d & 7))) * 8]);
                    oa[dt] = __builtin_amdgcn_mfma_f32_16x16x32_bf16(
                        pf[s], vf, oa[dt], 0, 0, 0);
                }
            }
            __builtin_amdgcn_s_setprio(0);
        }
    }

    // ---- normalize (broadcast per-row 1/l), write bf16 [B*N, C] ----
    const float linv = 1.f / lacc[0];
    const float v0 = __shfl(linv, lg * 4 + 0);
    const float v1 = __shfl(linv, lg * 4 + 1);
    const float v2 = __shfl(linv, lg * 4 + 2);
    const float v3 = __shfl(linv, lg * 4 + 3);
    const size_t orow0 = (size_t)b * SEQ + q0 + wid * 16;
    #pragma unroll
    for (int dt = 0; dt < 4; ++dt) {
        const int c = h * HD + dt * 16 + lr;
        aoutb[(orow0 + lg * 4 + 0) * DIM_C + c] = f2bf(oa[dt][0] * v0);
        aoutb[(orow0 + lg * 4 + 1) * DIM_C + c] = f2bf(oa[dt][1] * v1);
        aoutb[(orow0 + lg * 4 + 2) * DIM_C + c] = f2bf(oa[dt][2] * v2);
        aoutb[(orow0 + lg * 4 + 3) * DIM_C + c] = f2bf(oa[dt][3] * v3);
    }
}

// ---------------------------------------------------------------------------
extern "C" void kernel_launch(void* const* d_in, const int* in_sizes, int n_in,
                              void* d_out, int out_size, void* d_ws, size_t ws_size,
                              hipStream_t stream) {
    const float* x      = (const float*)d_in[0];
    const float* w_qkv  = (const float*)d_in[1];
    const float* b_qkv  = (const float*)d_in[2];
    const float* w_proj = (const float*)d_in[3];
    const float* b_proj = (const float*)d_in[4];
    float* out = (float*)d_out;

    const int M = BATCH * SEQ;                               // 8192
    ushort* xb     = (ushort*)d_ws;
    ushort* wqkvT  = xb     + (size_t)M * DIM_C;
    ushort* wprojT = wqkvT  + (size_t)3 * DIM_C * DIM_C;
    ushort* qkvb   = wprojT + (size_t)DIM_C * DIM_C;
    ushort* vt     = qkvb   + (size_t)M * 3 * DIM_C;
    ushort* aoutb  = vt     + (size_t)16 * HD * SEQ;

    convert_bf16<<<2048, 256, 0, stream>>>(x, xb, M * DIM_C / 4);
    transpose_w_bf16<<<dim3(3 * DIM_C / 64, DIM_C / 64), 256, 0, stream>>>(
        w_qkv, wqkvT, DIM_C, 3 * DIM_C);
    transpose_w_bf16<<<dim3(DIM_C / 64, DIM_C / 64), 256, 0, stream>>>(
        w_proj, wprojT, DIM_C, DIM_C);

    // QKV projection (bf16 out, Q pre-scaled)
    gemm_mfma<1><<<dim3(3 * DIM_C / 128, M / 128), 256, 0, stream>>>(
        xb, wqkvT, b_qkv, qkvb, M, 3 * DIM_C, DIM_C);

    transpose_v<<<dim3(SEQ / 64, BATCH * HEADS), 256, 0, stream>>>(qkvb, vt);

    flash_attn8<<<dim3(SEQ / 128, BATCH * HEADS), 512, 0, stream>>>(
        qkvb, vt, aoutb);

    gemm_mfma<0><<<dim3(DIM_C / 128, M / 128), 256, 0, stream>>>(
        aoutb, wprojT, b_proj, out, M, DIM_C, DIM_C);
}

// Round 14
// 235.876 us; speedup vs baseline: 1.1396x; 1.0302x over previous
//
#include <hip/hip_runtime.h>

#define DIM_C 512
#define HEADS 8
#define HD 64
#define BATCH 2
#define SEQ 4096
#define QSCALE (0.125f * 1.44269504088896f)   // 1/sqrt(64) * log2(e)

typedef __attribute__((ext_vector_type(8))) short short8;
typedef __attribute__((ext_vector_type(4))) float f32x4;

// fp32 -> bf16 round-to-nearest-even
__device__ __forceinline__ ushort f2bf(float f) {
    union { float f; unsigned u; } x; x.f = f;
    unsigned r = x.u + 0x7fffu + ((x.u >> 16) & 1u);
    return (ushort)(r >> 16);
}

// async global->LDS, 16B per lane. LDS dest = wave-uniform base + lane*16.
__device__ __forceinline__ void gl_lds16(const void* g, void* l) {
    __builtin_amdgcn_global_load_lds(
        (const __attribute__((address_space(1))) unsigned int*)g,
        (__attribute__((address_space(3))) unsigned int*)l, 16, 0, 0);
}

__device__ __forceinline__ unsigned cvt_pk_bf16(float lo, float hi) {
    unsigned w;
    asm("v_cvt_pk_bf16_f32 %0, %1, %2" : "=v"(w) : "v"(lo), "v"(hi));
    return w;
}

// bijective XCD swizzle (m204 simple form; requires nb % 8 == 0):
// XCD k (= dispatch slot % 8) executes a contiguous chunk of work ids.
__device__ __forceinline__ int xcd_swz(int j, int nb) {
    return (j & 7) * (nb >> 3) + (j >> 3);
}

// ---------------------------------------------------------------------------
// fused prep: [0,192) transpose w_qkv; [192,256) transpose w_proj;
// [256,2304) convert x -> bf16.  Bodies verbatim from the proven kernels.
// ---------------------------------------------------------------------------
__device__ __forceinline__ void tw_body(const float* __restrict__ in,
                                        ushort* __restrict__ out,
                                        ushort* Ls, int R, int C,
                                        int c0, int r0, int tid) {
    #pragma unroll
    for (int p = 0; p < 4; ++p) {
        const int idx = tid + p * 256;
        const int r = idx >> 4, c4 = (idx & 15) * 4;
        const float4 v = *reinterpret_cast<const float4*>(
            &in[(size_t)(r0 + r) * C + c0 + c4]);
        ushort4 o; o.x = f2bf(v.x); o.y = f2bf(v.y); o.z = f2bf(v.z); o.w = f2bf(v.w);
        *reinterpret_cast<ushort4*>(&Ls[r * 68 + c4]) = o;
    }
    __syncthreads();
    #pragma unroll
    for (int p = 0; p < 4; ++p) {
        const int idx = tid + p * 256;
        const int c = idx >> 4, r4 = (idx & 15) * 4;
        ushort4 o;
        o.x = Ls[(r4 + 0) * 68 + c]; o.y = Ls[(r4 + 1) * 68 + c];
        o.z = Ls[(r4 + 2) * 68 + c]; o.w = Ls[(r4 + 3) * 68 + c];
        *reinterpret_cast<ushort4*>(&out[(size_t)(c0 + c) * R + r0 + r4]) = o;
    }
}

__global__ __launch_bounds__(256)
void prep_fused(const float* __restrict__ x, ushort* __restrict__ xb,
                const float* __restrict__ w_qkv, ushort* __restrict__ wqkvT,
                const float* __restrict__ w_proj, ushort* __restrict__ wprojT,
                int n4) {
    __shared__ ushort Ls[64 * 68];
    const int j = blockIdx.x;
    const int tid = threadIdx.x;
    if (j < 192) {                       // w_qkv [512][1536] -> [1536][512]
        tw_body(w_qkv, wqkvT, Ls, 512, 1536, (j % 24) * 64, (j / 24) * 64, tid);
    } else if (j < 256) {                // w_proj [512][512] -> [512][512]
        const int jj = j - 192;
        tw_body(w_proj, wprojT, Ls, 512, 512, (jj % 8) * 64, (jj / 8) * 64, tid);
    } else {                             // x -> bf16, grid-stride
        int i = (j - 256) * 256 + tid;
        const int stride = 2048 * 256;
        for (; i < n4; i += stride) {
            const float4 v = reinterpret_cast<const float4*>(x)[i];
            ushort4 o;
            o.x = f2bf(v.x); o.y = f2bf(v.y); o.z = f2bf(v.z); o.w = f2bf(v.w);
            reinterpret_cast<ushort4*>(xb)[i] = o;
        }
    }
}

// V extract+transpose: qkvb [B*N,1536] cols 1024.. -> vt[bh][d=64][n=4096]
__global__ __launch_bounds__(256)
void transpose_v(const ushort* __restrict__ qkvb, ushort* __restrict__ vt) {
    __shared__ ushort Ls[64 * 68];
    const int tid = threadIdx.x;
    const int n0 = blockIdx.x * 64;
    const int bh = blockIdx.y, b = bh >> 3, h = bh & 7;
    #pragma unroll
    for (int p = 0; p < 4; ++p) {
        const int idx = tid + p * 256;
        const int r = idx >> 4, c4 = (idx & 15) * 4;
        const ushort4 v = *reinterpret_cast<const ushort4*>(
            &qkvb[(size_t)(b * SEQ + n0 + r) * 1536 + 1024 + h * 64 + c4]);
        *reinterpret_cast<ushort4*>(&Ls[r * 68 + c4]) = v;
    }
    __syncthreads();
    #pragma unroll
    for (int p = 0; p < 4; ++p) {
        const int idx = tid + p * 256;
        const int d = idx >> 4, n4 = (idx & 15) * 4;
        ushort4 o;
        o.x = Ls[(n4 + 0) * 68 + d]; o.y = Ls[(n4 + 1) * 68 + d];
        o.z = Ls[(n4 + 2) * 68 + d]; o.w = Ls[(n4 + 3) * 68 + d];
        *reinterpret_cast<ushort4*>(&vt[((size_t)bh * 64 + d) * SEQ + n0 + n4]) = o;
    }
}

// ---------------------------------------------------------------------------
// bf16 MFMA GEMM — round-6 proven body; 1D grid with XCD swizzle so each
// XCD owns contiguous row-panels (A-panel L2 reuse x N/128).
// MODE 0: fp32 out. MODE 1: bf16 out, cols<512 scaled by QSCALE.
// ---------------------------------------------------------------------------
template<int MODE>
__global__ __launch_bounds__(256)
void gemm_mfma(const ushort* __restrict__ A, const ushort* __restrict__ BT,
               const float* __restrict__ bias, void* __restrict__ Cout,
               int M, int N, int K) {
    __shared__ ushort As[128 * 64];
    __shared__ ushort Bs[128 * 64];
    const int tid = threadIdx.x;
    const int lane = tid & 63, wid = tid >> 6;
    const int lr = lane & 15, lg = lane >> 4;
    const int wm = wid >> 1, wn = wid & 1;
    const int nbx = N >> 7;
    const int wgid = xcd_swz(blockIdx.x, gridDim.x);
    const int rowBase = (wgid / nbx) * 128, colBase = (wgid % nbx) * 128;
    const int l8 = lane >> 3;
    const int lchunk = (lane & 7) ^ l8;

    f32x4 acc[4][4];
    #pragma unroll
    for (int i = 0; i < 4; ++i)
        #pragma unroll
        for (int j = 0; j < 4; ++j)
            #pragma unroll
            for (int c = 0; c < 4; ++c) acc[i][j][c] = 0.f;

    for (int k0 = 0; k0 < K; k0 += 64) {
        #pragma unroll
        for (int i = 0; i < 4; ++i) {
            const int r = wid * 32 + i * 8;
            gl_lds16(&A[(size_t)(rowBase + r + l8) * K + k0 + lchunk * 8],
                     &As[r * 64]);
            gl_lds16(&BT[(size_t)(colBase + r + l8) * K + k0 + lchunk * 8],
                     &Bs[r * 64]);
        }
        __syncthreads();
        #pragma unroll
        for (int s = 0; s < 2; ++s) {
            short8 af[4], bf[4];
            #pragma unroll
            for (int mt = 0; mt < 4; ++mt) {
                const int r = wm * 64 + mt * 16 + lr;
                af[mt] = *reinterpret_cast<const short8*>(
                    &As[r * 64 + ((s * 4 + lg) ^ (r & 7)) * 8]);
            }
            #pragma unroll
            for (int nt = 0; nt < 4; ++nt) {
                const int r = wn * 64 + nt * 16 + lr;
                bf[nt] = *reinterpret_cast<const short8*>(
                    &Bs[r * 64 + ((s * 4 + lg) ^ (r & 7)) * 8]);
            }
            #pragma unroll
            for (int mt = 0; mt < 4; ++mt)
                #pragma unroll
                for (int nt = 0; nt < 4; ++nt)
                    acc[mt][nt] = __builtin_amdgcn_mfma_f32_16x16x32_bf16(
                        af[mt], bf[nt], acc[mt][nt], 0, 0, 0);
        }
        __syncthreads();
    }

    #pragma unroll
    for (int nt = 0; nt < 4; ++nt) {
        const int col = colBase + wn * 64 + nt * 16 + lr;
        const float bv = bias[col];
        const float qs = (MODE == 1 && col < DIM_C) ? QSCALE : 1.f;
        #pragma unroll
        for (int mt = 0; mt < 4; ++mt) {
            #pragma unroll
            for (int j = 0; j < 4; ++j) {
                const int row = rowBase + wm * 64 + mt * 16 + lg * 4 + j;
                const float v = (acc[mt][nt][j] + bv) * qs;
                if (MODE == 0)
                    reinterpret_cast<float*>(Cout)[(size_t)row * N + col] = v;
                else
                    reinterpret_cast<ushort*>(Cout)[(size_t)row * N + col] = f2bf(v);
            }
        }
    }
}

// ---------------------------------------------------------------------------
// Flash attention v8b = round-12 v8 with:
//   (a) Ps swizzle reverted to the round-7 proven pair (rsw = lr&7) —
//       round-8/12 rsw measured WORSE (1.47e7 vs 4.2e6 conflicts);
//   (b) 1D grid + XCD swizzle: XCD k owns bh {2k,2k+1} -> K/V panels
//       (2MB) fully L2-resident per XCD (FETCH_SIZE 69.7MB -> expect ~45).
// All math/layout byte-identical to the passing round-12 kernel.
// ---------------------------------------------------------------------------
__global__ __launch_bounds__(512)
void flash_attn8(const ushort* __restrict__ qkvb, const ushort* __restrict__ vt,
                 ushort* __restrict__ aoutb) {
    __shared__ ushort Ks[2][128 * 64];  // 32 KB, [k][d] chunk-swizzled
    __shared__ ushort Vs[2][64 * 128];  // 32 KB, [d][k] chunk-swizzled
    __shared__ ushort Ps[8 * 16 * 64];  // 16 KB, per-wave P^T tile (reused 2x)

    const int tid = threadIdx.x;
    const int lane = tid & 63, wid = tid >> 6;      // 8 waves
    const int lr = lane & 15, lg = lane >> 4;
    const int wgid = xcd_swz(blockIdx.x, gridDim.x);
    const int qt = wgid & 31, bh = wgid >> 5;       // same-bh contiguous
    const int b = bh >> 3, h = bh & 7;
    const int q0 = qt * 128;
    const int l8 = lane >> 3;
    const int lchunk = (lane & 7) ^ l8;
    const int rsw = lr & 7;                         // round-7 proven swizzle

    // bf16 1.0 x8 fragment for the l-sum MFMA
    short8 onesf;
    #pragma unroll
    for (int i = 0; i < 8; ++i) onesf[i] = (short)0x3F80;

    // Q fragments (pre-scaled by QSCALE); B operand (col=lr=q-row)
    short8 qf[2];
    {
        const size_t qrow = (size_t)b * SEQ + q0 + wid * 16 + lr;
        #pragma unroll
        for (int s = 0; s < 2; ++s)
            qf[s] = *reinterpret_cast<const short8*>(
                &qkvb[qrow * 1536 + h * 64 + s * 32 + lg * 8]);
    }

    float m = -1e30f;                               // per-lane: row q=lr
    f32x4 lacc;
    lacc[0] = 0.f; lacc[1] = 0.f; lacc[2] = 0.f; lacc[3] = 0.f;
    f32x4 oa[4];
    #pragma unroll
    for (int dt = 0; dt < 4; ++dt)
        #pragma unroll
        for (int c = 0; c < 4; ++c) oa[dt][c] = 0.f;

    auto stage = [&](int kt, int buf) {
        const int k0 = kt * 128;
        #pragma unroll
        for (int i = 0; i < 2; ++i) {
            const int r = wid * 16 + i * 8;
            gl_lds16(&qkvb[(size_t)(b * SEQ + k0 + r + l8) * 1536 + DIM_C +
                           h * 64 + lchunk * 8],
                     &Ks[buf][r * 64]);
        }
        #pragma unroll
        for (int i = 0; i < 2; ++i) {
            const int d0 = wid * 8 + i * 4;
            const int d = d0 + (lane >> 4);
            const int c16 = lane & 15;
            const int gch = (c16 & 8) | ((c16 & 7) ^ (d & 7));
            gl_lds16(&vt[((size_t)bh * 64 + d) * SEQ + k0 + gch * 8],
                     &Vs[buf][d0 * 128]);
        }
    };

    stage(0, 0);
    const int NT = SEQ / 128;                       // 32 iterations
    for (int kt = 0; kt < NT; ++kt) {
        const int buf = kt & 1;
        __syncthreads();                            // stage(kt) complete
        if (kt + 1 < NT) stage(kt + 1, buf ^ 1);    // prefetch overlaps compute

        // ---- S^T = K @ Q^T over 128 k-rows ----
        f32x4 sa[8];
        #pragma unroll
        for (int t = 0; t < 8; ++t)
            #pragma unroll
            for (int c = 0; c < 4; ++c) sa[t][c] = 0.f;
        __builtin_amdgcn_s_setprio(1);
        #pragma unroll
        for (int t = 0; t < 8; ++t) {
            const int n = t * 16 + lr;
            #pragma unroll
            for (int s = 0; s < 2; ++s) {
                const short8 kf = *reinterpret_cast<const short8*>(
                    &Ks[buf][n * 64 + ((s * 4 + lg) ^ (n & 7)) * 8]);
                sa[t] = __builtin_amdgcn_mfma_f32_16x16x32_bf16(
                    kf, qf[s], sa[t], 0, 0, 0);
            }
        }
        __builtin_amdgcn_s_setprio(0);

        // ---- per-lane row max (max3 triples), defer-max THR=8 ----
        float mx = fmaxf(fmaxf(sa[0][0], sa[0][1]), sa[0][2]);
        #pragma unroll
        for (int t = 1; t < 8; ++t)
            mx = fmaxf(fmaxf(mx, sa[t][0]),
                       fmaxf(fmaxf(sa[t][1], sa[t][2]), sa[t][3]));
        mx = fmaxf(mx, sa[0][3]);
        mx = fmaxf(mx, __shfl_xor(mx, 16));
        mx = fmaxf(mx, __shfl_xor(mx, 32));
        if (__any(mx > m + 8.f)) {                  // rare, wave-uniform
            const float mnew = fmaxf(m, mx);
            const float alpha = exp2f(m - mnew);
            m = mnew;
            lacc[0] *= alpha; lacc[1] *= alpha;
            lacc[2] *= alpha; lacc[3] *= alpha;
            const float a0 = __shfl(alpha, lg * 4 + 0);
            const float a1 = __shfl(alpha, lg * 4 + 1);
            const float a2 = __shfl(alpha, lg * 4 + 2);
            const float a3 = __shfl(alpha, lg * 4 + 3);
            #pragma unroll
            for (int dt = 0; dt < 4; ++dt) {
                oa[dt][0] *= a0; oa[dt][1] *= a1;
                oa[dt][2] *= a2; oa[dt][3] *= a3;
            }
        }
        #pragma unroll
        for (int t = 0; t < 8; ++t)
            #pragma unroll
            for (int r = 0; r < 4; ++r)
                sa[t][r] = exp2f(sa[t][r] - m);

        // ---- two k-halves: pack P^T -> Ps (reused), PV + l-sum ----
        const int pb = wid * (16 * 64);
        const int pbase = pb + lr * 64 + (lg & 1) * 4;
        #pragma unroll
        for (int kh = 0; kh < 2; ++kh) {
            #pragma unroll
            for (int t = 0; t < 4; ++t) {
                const int chunk = (2 * t + (lg >> 1)) ^ rsw;
                uint2 w;
                w.x = cvt_pk_bf16(sa[kh * 4 + t][0], sa[kh * 4 + t][1]);
                w.y = cvt_pk_bf16(sa[kh * 4 + t][2], sa[kh * 4 + t][3]);
                *reinterpret_cast<uint2*>(&Ps[pbase + chunk * 8]) = w;
            }
            short8 pf[2];
            #pragma unroll
            for (int s = 0; s < 2; ++s)
                pf[s] = *reinterpret_cast<const short8*>(
                    &Ps[pb + lr * 64 + ((lg + 4 * s) ^ rsw) * 8]);

            __builtin_amdgcn_s_setprio(1);
            #pragma unroll
            for (int s = 0; s < 2; ++s)
                lacc = __builtin_amdgcn_mfma_f32_16x16x32_bf16(
                    onesf, pf[s], lacc, 0, 0, 0);
            #pragma unroll
            for (int dt = 0; dt < 4; ++dt) {
                const int d = dt * 16 + lr;
                #pragma unroll
                for (int s = 0; s < 2; ++s) {
                    const short8 vf = *reinterpret_cast<const short8*>(
                        &Vs[buf][d * 128 +
                                 (kh * 8 + ((s * 4 + lg) ^ (d & 7))) * 8]);
                    oa[dt] = __builtin_amdgcn_mfma_f32_16x16x32_bf16(
                        pf[s], vf, oa[dt], 0, 0, 0);
                }
            }
            __builtin_amdgcn_s_setprio(0);
        }
    }

    // ---- normalize (broadcast per-row 1/l), write bf16 [B*N, C] ----
    const float linv = 1.f / lacc[0];
    const float v0 = __shfl(linv, lg * 4 + 0);
    const float v1 = __shfl(linv, lg * 4 + 1);
    const float v2 = __shfl(linv, lg * 4 + 2);
    const float v3 = __shfl(linv, lg * 4 + 3);
    const size_t orow0 = (size_t)b * SEQ + q0 + wid * 16;
    #pragma unroll
    for (int dt = 0; dt < 4; ++dt) {
        const int c = h * HD + dt * 16 + lr;
        aoutb[(orow0 + lg * 4 + 0) * DIM_C + c] = f2bf(oa[dt][0] * v0);
        aoutb[(orow0 + lg * 4 + 1) * DIM_C + c] = f2bf(oa[dt][1] * v1);
        aoutb[(orow0 + lg * 4 + 2) * DIM_C + c] = f2bf(oa[dt][2] * v2);
        aoutb[(orow0 + lg * 4 + 3) * DIM_C + c] = f2bf(oa[dt][3] * v3);
    }
}

// ---------------------------------------------------------------------------
extern "C" void kernel_launch(void* const* d_in, const int* in_sizes, int n_in,
                              void* d_out, int out_size, void* d_ws, size_t ws_size,
                              hipStream_t stream) {
    const float* x      = (const float*)d_in[0];
    const float* w_qkv  = (const float*)d_in[1];
    const float* b_qkv  = (const float*)d_in[2];
    const float* w_proj = (const float*)d_in[3];
    const float* b_proj = (const float*)d_in[4];
    float* out = (float*)d_out;

    const int M = BATCH * SEQ;                               // 8192
    ushort* xb     = (ushort*)d_ws;
    ushort* wqkvT  = xb     + (size_t)M * DIM_C;
    ushort* wprojT = wqkvT  + (size_t)3 * DIM_C * DIM_C;
    ushort* qkvb   = wprojT + (size_t)DIM_C * DIM_C;
    ushort* vt     = qkvb   + (size_t)M * 3 * DIM_C;
    ushort* aoutb  = vt     + (size_t)16 * HD * SEQ;

    // fused prep: both weight transposes + x->bf16
    prep_fused<<<2304, 256, 0, stream>>>(x, xb, w_qkv, wqkvT, w_proj, wprojT,
                                         M * DIM_C / 4);

    // QKV projection (bf16 out, Q pre-scaled); 1D grid, XCD-swizzled
    gemm_mfma<1><<<(3 * DIM_C / 128) * (M / 128), 256, 0, stream>>>(
        xb, wqkvT, b_qkv, qkvb, M, 3 * DIM_C, DIM_C);

    transpose_v<<<dim3(SEQ / 64, BATCH * HEADS), 256, 0, stream>>>(qkvb, vt);

    flash_attn8<<<(SEQ / 128) * (BATCH * HEADS), 512, 0, stream>>>(
        qkvb, vt, aoutb);

    gemm_mfma<0><<<(DIM_C / 128) * (M / 128), 256, 0, stream>>>(
        aoutb, wprojT, b_proj, out, M, DIM_C, DIM_C);
}